// Round 3
// baseline (452.025 us; speedup 1.0000x reference)
//
#include <hip/hip_runtime.h>
#include <stdint.h>

// ---------------------------------------------------------------------------
// EW_MHSA_Hybrid: x(32,256,56,56) --1x1conv--> qk(512ch), v(256ch,ReLU)
// then 7x7 window attention over remote (dilated) + close (contiguous)
// partitions, summed. Output fp32 (32,256,56,56).
//
// ws layout (needs ~258 MB):
//   [0, 393216)             Wb  : bf16 weights [768 rows][256 ch] LINEAR
//   [393216, 51773440)      xT  : bf16 x pixel-major [b*3136+p][256] LINEAR
//                                 (DEAD after k_conv -> reused as oR)
//   [51773440, 205914112)   qkv : bf16 [b*3136+p][768] (q|k|v; q pre-scaled by
//                                 SCALE*log2e; v has ReLU)
//
// k_conv is LDS-FREE: weights (384 KB, L2-hot) and xT (1.6 MB/batch, L2-fit
// with XCD-batch affinity) are loaded directly global->VGPR as MFMA frags
// via 8 per-lane base addresses + compile-time immediate offsets. No
// barriers in the K-loop. LDS (32 KB) only for the epilogue transpose.
//
// Attention is two passes: remote pass writes bf16 oR (pixel-major);
// close pass reads oR, adds its own fp32 result and writes NCHW out
// directly (k_merge fused away).
// ---------------------------------------------------------------------------

typedef float f32x4 __attribute__((ext_vector_type(4)));
typedef __attribute__((ext_vector_type(8))) short short8;

union V16 { uint4 u; short8 s; unsigned short h[8]; };

__device__ __forceinline__ unsigned short f2bf(float f) {      // RNE
  union { float f; uint32_t u; } a; a.f = f;
  uint32_t u = a.u;
  return (unsigned short)((u + 0x7FFFu + ((u >> 16) & 1u)) >> 16);
}

__device__ __forceinline__ unsigned short f2bf_rhu(float f) {  // round-half-up
  union { float f; uint32_t u; } a; a.f = f;
  return (unsigned short)((a.u + 0x8000u) >> 16);
}

__device__ __forceinline__ float bf2f(uint32_t bits_hi16) {
  union { uint32_t u; float f; } a; a.u = bits_hi16; return a.f;
}

// ------------------- kernel 0: weight convert (linear) ----------------------
__global__ __launch_bounds__(256) void k_wconv(const float* __restrict__ qk_w,
                                               const float* __restrict__ v_w,
                                               unsigned short* __restrict__ Wb) {
  int i = blockIdx.x * 256 + threadIdx.x;   // 768*32 = 24576 threads, 16B each
  int o = i >> 5, gidx = i & 31;
  int c0 = gidx * 8;
  const float* src = (o < 512) ? (qk_w + o * 256 + c0) : (v_w + (o - 512) * 256 + c0);
  unsigned short vv[8];
#pragma unroll
  for (int j = 0; j < 8; j++) vv[j] = f2bf(src[j]);
  uint4 u;
  u.x = (uint32_t)vv[0] | ((uint32_t)vv[1] << 16);
  u.y = (uint32_t)vv[2] | ((uint32_t)vv[3] << 16);
  u.z = (uint32_t)vv[4] | ((uint32_t)vv[5] << 16);
  u.w = (uint32_t)vv[6] | ((uint32_t)vv[7] << 16);
  *(uint4*)(Wb + (size_t)o * 256 + c0) = u;
}

// --------------------- kernel 1: x -> bf16 NHWC (linear) --------------------
__global__ __launch_bounds__(256) void k_xpose(const float* __restrict__ x,
                                               unsigned short* __restrict__ xT) {
  const int t = threadIdx.x;
  const int p = blockIdx.x * 64 + (t >> 2);
  const int sub = t & 3;
  const int c0 = blockIdx.y * 32 + sub * 8;
  const int b = blockIdx.z;
  const float* xp = x + ((size_t)(b * 256 + c0)) * 3136 + p;
  unsigned short vv[8];
#pragma unroll
  for (int j = 0; j < 8; j++) vv[j] = f2bf(xp[(size_t)j * 3136]);
  uint4 u;
  u.x = (uint32_t)vv[0] | ((uint32_t)vv[1] << 16);
  u.y = (uint32_t)vv[2] | ((uint32_t)vv[3] << 16);
  u.z = (uint32_t)vv[4] | ((uint32_t)vv[5] << 16);
  u.w = (uint32_t)vv[6] | ((uint32_t)vv[7] << 16);
  *(uint4*)(xT + ((size_t)(b * 3136 + p)) * 256 + c0) = u;
}

// ------------------------- kernel 2: conv GEMM (MFMA) -----------------------
// grid flat 4800 with XCD-batch affinity. LDS-free main loop: A (weights) and
// B (xT) frags loaded global->VGPR (L2-resident), imm-offset addressing,
// zero K-loop barriers. Epilogue: LDS transpose -> qkv written as contiguous
// 256 B channel segments. q channels (ot<2) pre-scaled by SCALE*log2e.
__global__ __launch_bounds__(256) void k_conv(const unsigned short* __restrict__ Wb,
                                              const unsigned short* __restrict__ xT,
                                              unsigned short* __restrict__ qkv) {
  __shared__ uint4 lds4[2048];     // 32 KB, epilogue transpose only
  char* lds = (char*)lds4;
  const int bi = blockIdx.x;                 // 0..4799
  const int xcd = bi & 7, g = bi >> 3;       // g: 0..599
  const int bgrp = g / 150;
  const int rem = g - bgrp * 150;
  const int b = xcd + 8 * bgrp;
  const int ot = rem / 25;
  const int pt = rem - ot * 25;
  const int p0 = pt * 128, o0 = ot * 128;
  const bool isv = (ot >= 4);
  const float qs = (ot < 2) ? 0.18033688011112042f : 1.0f;  // SCALE*log2(e)

  const int tid = threadIdx.x;
  const int lane = tid & 63, wave = tid >> 6;
  const int lid = lane & 15, quad = lane >> 4;
  const int m_off = (wave & 1) * 64, n_off = (wave >> 1) * 64;
  const size_t rowb = (size_t)(b * 3136 + p0);

  // Per-lane frag base addresses (row stride 512 B; quad picks 16 B sub-chunk).
  // Frag (t, ks) lives at base + t*128 + ks*64  (imm offsets, all < 4096).
  const char* baseA[4];
  const char* baseB[4];
#pragma unroll
  for (int mi = 0; mi < 4; mi++)
    baseA[mi] = (const char*)Wb + (size_t)(o0 + m_off + mi * 16 + lid) * 512 + quad * 16;
#pragma unroll
  for (int ni = 0; ni < 4; ni++)
    baseB[ni] = (const char*)xT + (rowb + n_off + ni * 16 + lid) * 512 + quad * 16;
  // NOTE: for the last pixel tile, baseB rows run past 3136 px; those reads
  // land inside qkv (allocated) and their results are discarded (px<3136
  // guard at the store). No faults, no stores of garbage.

  f32x4 acc[4][4];
#pragma unroll
  for (int mi = 0; mi < 4; mi++)
#pragma unroll
    for (int ni = 0; ni < 4; ni++) { f32x4 z = {0.f, 0.f, 0.f, 0.f}; acc[mi][ni] = z; }

#pragma unroll
  for (int t = 0; t < 4; t++) {              // K-step: k = t*64 .. t*64+63
    V16 a[4][2], bv[4][2];
#pragma unroll
    for (int mi = 0; mi < 4; mi++)
#pragma unroll
      for (int ks = 0; ks < 2; ks++)
        a[mi][ks].u = *(const uint4*)(baseA[mi] + t * 128 + ks * 64);
#pragma unroll
    for (int ni = 0; ni < 4; ni++)
#pragma unroll
      for (int ks = 0; ks < 2; ks++)
        bv[ni][ks].u = *(const uint4*)(baseB[ni] + t * 128 + ks * 64);
#pragma unroll
    for (int mi = 0; mi < 4; mi++)
#pragma unroll
      for (int ni = 0; ni < 4; ni++) {
        acc[mi][ni] = __builtin_amdgcn_mfma_f32_16x16x32_bf16(a[mi][0].s, bv[ni][0].s, acc[mi][ni], 0, 0, 0);
        acc[mi][ni] = __builtin_amdgcn_mfma_f32_16x16x32_bf16(a[mi][1].s, bv[ni][1].s, acc[mi][ni], 0, 0, 0);
      }
  }

  // ---- epilogue: stage bf16 tile [128 px][256 B of ch] in LDS (swizzled),
  //      then write qkv as contiguous 256 B channel segments per pixel ----
#pragma unroll
  for (int mi = 0; mi < 4; mi++) {
    const int chunkb = (m_off >> 3) + mi * 2 + (quad >> 1);
#pragma unroll
    for (int ni = 0; ni < 4; ni++) {
      const int pxl = n_off + ni * 16 + lid;
      f32x4 v = acc[mi][ni];
      v.x *= qs; v.y *= qs; v.z *= qs; v.w *= qs;
      if (isv) {
        v.x = fmaxf(v.x, 0.f); v.y = fmaxf(v.y, 0.f);
        v.z = fmaxf(v.z, 0.f); v.w = fmaxf(v.w, 0.f);
      }
      uint32_t lo = (uint32_t)f2bf(v.x) | ((uint32_t)f2bf(v.y) << 16);
      uint32_t hi = (uint32_t)f2bf(v.z) | ((uint32_t)f2bf(v.w) << 16);
      uint2 st; st.x = lo; st.y = hi;
      *(uint2*)(lds + pxl * 256 + ((chunkb ^ (pxl & 7)) << 4) + (quad & 1) * 8) = st;
    }
  }
  __syncthreads();

#pragma unroll
  for (int rep = 0; rep < 8; rep++) {
    int idx = rep * 256 + tid;
    int pxl = idx >> 4, seg = idx & 15;
    uint4 vv = *(const uint4*)(lds + pxl * 256 + ((seg ^ (pxl & 7)) << 4));
    int px = p0 + pxl;
    if (px < 3136)
      *(uint4*)((char*)qkv + ((size_t)(b * 3136 + px)) * 1536 + o0 * 2 + seg * 16) = vv;
  }
}

// --------------------------- kernel 3: attention ----------------------------
// One block per (window, batch), XCD-batch affinity; wave = head.
// Operand-swapped score: St = K Q^T (MFMA, C rows=key cols=q), so each lane
// holds 4 ADJACENT keys for a fixed q -> P packed as b64 LDS writes, masking
// only in the statically-known mi==3 tile.
// PART: 0=remote (dilated), 1=close (contiguous).
// FUSED: close pass reads oPrev (=oR) and writes fp32 NCHW out directly.
template <int PART, int FUSED>
__global__ __launch_bounds__(256) void k_attn_t(const unsigned short* __restrict__ qkv,
                                                const unsigned short* __restrict__ oPrev,
                                                unsigned short* __restrict__ oDst,
                                                float* __restrict__ out) {
  __shared__ uint4 smem4[2048];   // 32 KB = 4 waves x 8 KB P-buffer
  const int bi = blockIdx.x;                  // 0..2047
  const int xcd = bi & 7, g = bi >> 3;        // g: 0..255
  const int b = ((g >> 6) << 3) + xcd;        // batch: b%8 == xcd
  const int w = g & 63;
  const int i1 = w >> 3, i2 = w & 7;
  const int off = PART ? (i1 * 392 + i2 * 7) : (i1 * 56 + i2);
  const int sh  = PART ? 56 : 448;            // compile-time per instantiation
  const int sw  = PART ? 1 : 8;

  const int lane = threadIdx.x & 63;
  const int head = threadIdx.x >> 6;
  const int lid = lane & 15, quad = lane >> 4;
  char* Pb = (char*)smem4 + head * 8192;
  const unsigned short* __restrict__ qkvb = qkv + (size_t)b * 3136 * 768;

  auto pix = [&](int t) -> int {  // window slot t (0..48) -> pixel index
    int h1 = (t * 37) >> 8;       // t/7 for t<=48
    int w1 = t - h1 * 7;
    return off + h1 * sh + w1 * sw;
  };

  // --- V^T A-frags: A[m=ch][k=key]; lane m=lid -> ch = mi*16+lid ---
  V16 va[4][2];
#pragma unroll
  for (int ks = 0; ks < 2; ks++)
#pragma unroll
    for (int j = 0; j < 8; j++) {
      int key = ks * 32 + quad * 8 + j;
      int p = pix(min(key, 48));               // clamp; P cols >=49 are 0
      const unsigned short* vp = qkvb + p * 768 + 512 + head * 64 + lid;
#pragma unroll
      for (int mi = 0; mi < 4; mi++) va[mi][ks].h[j] = vp[mi * 16];
    }

  // --- Q / K frags (16B per lane). K is the A operand (rows=key). ---
  V16 qf[4][2], kf[4][2];
#pragma unroll
  for (int mi = 0; mi < 4; mi++) {
    int p = pix(min(mi * 16 + lid, 48));
    const unsigned short* qp = qkvb + p * 768 + head * 64;
#pragma unroll
    for (int ks = 0; ks < 2; ks++) qf[mi][ks].u = *(const uint4*)(qp + ks * 32 + quad * 8);
  }
#pragma unroll
  for (int ni = 0; ni < 4; ni++) {
    int p = pix(min(ni * 16 + lid, 48));
    const unsigned short* kp = qkvb + p * 768 + 256 + head * 64;
#pragma unroll
    for (int ks = 0; ks < 2; ks++) kf[ni][ks].u = *(const uint4*)(kp + ks * 32 + quad * 8);
  }

  // --- St = K Q^T (q pre-scaled by SCALE*log2e in k_conv) ---
  //     lane holds St[key = mi*16+quad*4+r][q = ni*16+lid]
  f32x4 s[4][4];
#pragma unroll
  for (int mi = 0; mi < 4; mi++)
#pragma unroll
    for (int ni = 0; ni < 4; ni++) {
      f32x4 z = {0.f, 0.f, 0.f, 0.f};
      z = __builtin_amdgcn_mfma_f32_16x16x32_bf16(kf[mi][0].s, qf[ni][0].s, z, 0, 0, 0);
      z = __builtin_amdgcn_mfma_f32_16x16x32_bf16(kf[mi][1].s, qf[ni][1].s, z, 0, 0, 0);
      s[mi][ni] = z;
    }

  // --- unnormalized P = exp2(St): 4 adjacent keys/lane -> packed b64 writes
  //     into row-major-swizzled P[q][key] (same layout the pt reads expect).
  //     Keys >= 49 exist only in mi==3 (valid only quad==0, r==0). ---
  {
    const int rx = lid & 7;
    char* wbase = Pb + lid * 128 + (quad & 1) * 8;
#pragma unroll
    for (int mi = 0; mi < 4; mi++) {
      const int swz = ((mi * 2 + (quad >> 1)) ^ rx) << 4;
#pragma unroll
      for (int ni = 0; ni < 4; ni++) {
        uint32_t d0, d1;
        if (mi < 3) {
          d0 = (uint32_t)f2bf_rhu(__builtin_amdgcn_exp2f(s[mi][ni][0]))
             | ((uint32_t)f2bf_rhu(__builtin_amdgcn_exp2f(s[mi][ni][1])) << 16);
          d1 = (uint32_t)f2bf_rhu(__builtin_amdgcn_exp2f(s[mi][ni][2]))
             | ((uint32_t)f2bf_rhu(__builtin_amdgcn_exp2f(s[mi][ni][3])) << 16);
        } else {
          d0 = quad ? 0u : (uint32_t)f2bf_rhu(__builtin_amdgcn_exp2f(s[3][ni][0]));
          d1 = 0u;
        }
        uint2 st; st.x = d0; st.y = d1;
        *(uint2*)(wbase + ni * 2048 + swz) = st;
      }
    }
  }
  __syncthreads();   // DS ordering fence (writes above are re-read below)

  // --- P^T B-frags: B[k=key][n=q]; lane n=lid -> q = ni*16+lid ---
  V16 pt[4][2];
#pragma unroll
  for (int ni = 0; ni < 4; ni++) {
    int row = ni * 16 + lid;                   // q row of P
#pragma unroll
    for (int ks = 0; ks < 2; ks++) {
      int gl = ks * 4 + quad;
      pt[ni][ks].u = *(const uint4*)(Pb + row * 128 + ((gl ^ (row & 7)) << 4));
    }
  }

  // --- rowsum(q) via ones-A MFMA: D[.][q] = sum_k P^T[k][q] ---
  V16 ones;
#pragma unroll
  for (int j = 0; j < 8; j++) ones.h[j] = 0x3F80;   // bf16 1.0
  float inv[4];
  int pq[4]; bool qv[4];
#pragma unroll
  for (int ni = 0; ni < 4; ni++) {
    f32x4 z = {0.f, 0.f, 0.f, 0.f};
    z = __builtin_amdgcn_mfma_f32_16x16x32_bf16(ones.s, pt[ni][0].s, z, 0, 0, 0);
    z = __builtin_amdgcn_mfma_f32_16x16x32_bf16(ones.s, pt[ni][1].s, z, 0, 0, 0);
    inv[ni] = __builtin_amdgcn_rcpf(z[0]);
    int q = ni * 16 + lid;
    qv[ni] = q < 49;
    pq[ni] = pix(qv[ni] ? q : 48);
  }

  // --- O^T = V^T P^T; C-layout: row=ch (4 consecutive per lane), col=q ---
#pragma unroll
  for (int mi = 0; mi < 4; mi++) {
    f32x4 om[4];
#pragma unroll
    for (int ni = 0; ni < 4; ni++) {
      f32x4 z = {0.f, 0.f, 0.f, 0.f};
      z = __builtin_amdgcn_mfma_f32_16x16x32_bf16(va[mi][0].s, pt[ni][0].s, z, 0, 0, 0);
      z = __builtin_amdgcn_mfma_f32_16x16x32_bf16(va[mi][1].s, pt[ni][1].s, z, 0, 0, 0);
      om[ni] = z;
    }
    if constexpr (!FUSED) {
      // remote pass: bf16 pixel-major store
      unsigned short* __restrict__ oSb = oDst + (size_t)b * 3136 * 256;
#pragma unroll
      for (int ni = 0; ni < 4; ni++) {
        if (qv[ni]) {
          float iv = inv[ni];
          uint32_t lo = ((uint32_t)f2bf_rhu(om[ni][0] * iv)) | ((uint32_t)f2bf_rhu(om[ni][1] * iv) << 16);
          uint32_t hi = ((uint32_t)f2bf_rhu(om[ni][2] * iv)) | ((uint32_t)f2bf_rhu(om[ni][3] * iv) << 16);
          uint2 st; st.x = lo; st.y = hi;
          *(uint2*)(oSb + pq[ni] * 256 + head * 64 + mi * 16 + quad * 4) = st;
        }
      }
    } else {
      // close pass: add remote result (bf16, pixel-major) and write fp32 NCHW
      const unsigned short* __restrict__ oPb = oPrev + (size_t)b * 3136 * 256;
      float* __restrict__ outb = out + (size_t)b * 256 * 3136;
      const int c0 = head * 64 + mi * 16 + quad * 4;
#pragma unroll
      for (int ni = 0; ni < 4; ni++) {
        if (qv[ni]) {
          float iv = inv[ni];
          uint2 r = *(const uint2*)(oPb + pq[ni] * 256 + c0);
          float o0 = om[ni][0] * iv + bf2f(r.x << 16);
          float o1 = om[ni][1] * iv + bf2f(r.x & 0xFFFF0000u);
          float o2 = om[ni][2] * iv + bf2f(r.y << 16);
          float o3 = om[ni][3] * iv + bf2f(r.y & 0xFFFF0000u);
          float* op = outb + (size_t)c0 * 3136 + pq[ni];
          op[0]        = o0;
          op[3136]     = o1;
          op[2 * 3136] = o2;
          op[3 * 3136] = o3;
        }
      }
    }
  }
}

// ------------------------------- launcher -----------------------------------
extern "C" void kernel_launch(void* const* d_in, const int* in_sizes, int n_in,
                              void* d_out, int out_size, void* d_ws, size_t ws_size,
                              hipStream_t stream) {
  (void)in_sizes; (void)n_in; (void)out_size; (void)ws_size;
  const float* x    = (const float*)d_in[0];
  const float* qk_w = (const float*)d_in[1];
  const float* v_w  = (const float*)d_in[2];
  float* out = (float*)d_out;
  char* ws = (char*)d_ws;
  unsigned short* Wb  = (unsigned short*)ws;                    //     393,216 B
  unsigned short* xT  = (unsigned short*)(ws + 393216);         //  51,380,224 B (reused as oR)
  unsigned short* qkv = (unsigned short*)(ws + 51773440ull);    // 154,140,672 B
  unsigned short* oR  = xT;                                     // alias (xT dead after k_conv)

  hipLaunchKernelGGL(k_wconv, dim3(96), dim3(256), 0, stream, qk_w, v_w, Wb);
  hipLaunchKernelGGL(k_xpose, dim3(49, 8, 32), dim3(256), 0, stream, x, xT);
  hipLaunchKernelGGL(k_conv, dim3(4800), dim3(256), 0, stream, Wb, xT, qkv);
  hipLaunchKernelGGL(HIP_KERNEL_NAME(k_attn_t<0, 0>), dim3(2048), dim3(256), 0, stream,
                     qkv, (const unsigned short*)nullptr, oR, (float*)nullptr);
  hipLaunchKernelGGL(HIP_KERNEL_NAME(k_attn_t<1, 1>), dim3(2048), dim3(256), 0, stream,
                     qkv, (const unsigned short*)oR, (unsigned short*)nullptr, out);
}

// Round 5
// 354.969 us; speedup vs baseline: 1.2734x; 1.2734x over previous
//
#include <hip/hip_runtime.h>
#include <stdint.h>

// ---------------------------------------------------------------------------
// EW_MHSA_Hybrid: x(32,256,56,56) --1x1conv--> qk(512ch), v(256ch,ReLU)
// then 7x7 window attention over remote (dilated) + close (contiguous)
// partitions, summed. Output fp32 (32,256,56,56).
//
// ws layout (needs ~258 MB):
//   [0, 393216)             Wb  : bf16 weights [768 rows][512 B], XOR-swizzled
//   [393216, 51773440)      xT  : bf16 x pixel-major [b*3136+p][256], swizzled
//                                 (DEAD after k_conv -> reused as oR)
//   [51773440, 205914112)   qkv : bf16 [b*3136+p][768] (q|k|v; q pre-scaled by
//                                 SCALE*log2e; v has ReLU)
//
// k_conv: round-1 proven staging (single 32 KB A|B LDS buffer, global_load_lds,
// 2 barriers/K-step — 64 KB dbuf REGRESSED via occupancy, LDS-free REGRESSED
// via VMEM scatter) + round-2 proven epilogue (LDS transpose reusing the same
// 32 KB -> qkv written as contiguous 256 B channel segments).
//
// Attention is two passes: remote pass writes bf16 oR (pixel-major);
// close pass reads oR, adds its own fp32 result and writes NCHW out
// directly (k_merge fused away).
// ---------------------------------------------------------------------------

typedef float f32x4 __attribute__((ext_vector_type(4)));
typedef __attribute__((ext_vector_type(8))) short short8;

union V16 { uint4 u; short8 s; unsigned short h[8]; };

typedef const __attribute__((address_space(1))) uint32_t* gp_t;
typedef __attribute__((address_space(3))) uint32_t* lp_t;

__device__ __forceinline__ void async16(const void* g, void* l) {
  __builtin_amdgcn_global_load_lds((gp_t)g, (lp_t)l, 16, 0, 0);
}

__device__ __forceinline__ unsigned short f2bf(float f) {      // RNE
  union { float f; uint32_t u; } a; a.f = f;
  uint32_t u = a.u;
  return (unsigned short)((u + 0x7FFFu + ((u >> 16) & 1u)) >> 16);
}

__device__ __forceinline__ unsigned short f2bf_rhu(float f) {  // round-half-up
  union { float f; uint32_t u; } a; a.f = f;
  return (unsigned short)((a.u + 0x8000u) >> 16);
}

__device__ __forceinline__ float bf2f(uint32_t bits_hi16) {
  union { uint32_t u; float f; } a; a.u = bits_hi16; return a.f;
}

// ------------------- kernel 0: weight convert (swizzled) --------------------
__global__ __launch_bounds__(256) void k_wconv(const float* __restrict__ qk_w,
                                               const float* __restrict__ v_w,
                                               unsigned short* __restrict__ Wb) {
  int i = blockIdx.x * 256 + threadIdx.x;   // 768*32 = 24576 threads, 16B each
  int o = i >> 5, gidx = i & 31;
  int c0 = gidx * 8;
  const float* src = (o < 512) ? (qk_w + o * 256 + c0) : (v_w + (o - 512) * 256 + c0);
  unsigned short vv[8];
#pragma unroll
  for (int j = 0; j < 8; j++) vv[j] = f2bf(src[j]);
  uint4 u;
  u.x = (uint32_t)vv[0] | ((uint32_t)vv[1] << 16);
  u.y = (uint32_t)vv[2] | ((uint32_t)vv[3] << 16);
  u.z = (uint32_t)vv[4] | ((uint32_t)vv[5] << 16);
  u.w = (uint32_t)vv[6] | ((uint32_t)vv[7] << 16);
  int kb = gidx >> 3, gg = gidx & 7;
  char* dst = (char*)Wb + (size_t)o * 512 + kb * 128 + ((gg ^ (o & 7)) << 4);
  *(uint4*)dst = u;
}

// --------------------- kernel 1: x -> bf16 NHWC (swizzled) ------------------
__global__ __launch_bounds__(256) void k_xpose(const float* __restrict__ x,
                                               unsigned short* __restrict__ xT) {
  const int t = threadIdx.x;
  const int p = blockIdx.x * 64 + (t >> 2);
  const int sub = t & 3;
  const int c0 = blockIdx.y * 32 + sub * 8;
  const int b = blockIdx.z;
  const float* xp = x + ((size_t)(b * 256 + c0)) * 3136 + p;
  unsigned short vv[8];
#pragma unroll
  for (int j = 0; j < 8; j++) vv[j] = f2bf(xp[(size_t)j * 3136]);
  uint4 u;
  u.x = (uint32_t)vv[0] | ((uint32_t)vv[1] << 16);
  u.y = (uint32_t)vv[2] | ((uint32_t)vv[3] << 16);
  u.z = (uint32_t)vv[4] | ((uint32_t)vv[5] << 16);
  u.w = (uint32_t)vv[6] | ((uint32_t)vv[7] << 16);
  const int g = (c0 >> 3) & 7;
  const int kb = c0 >> 6;
  char* dst = (char*)xT + ((size_t)(b * 3136 + p)) * 512 + kb * 128 + ((g ^ (p & 7)) << 4);
  *(uint4*)dst = u;
}

// ------------------------- kernel 2: conv GEMM (MFMA) -----------------------
// grid flat 4800 with XCD-batch affinity. A (W) and B (x) via global_load_lds
// into a single 32 KB buffer, 2 barriers per K-step (round-1 structure).
// Epilogue reuses the same 32 KB: LDS transpose -> qkv written as contiguous
// 256 B channel segments. q channels (ot<2) pre-scaled by SCALE*log2e.
__global__ __launch_bounds__(256) void k_conv(const unsigned short* __restrict__ Wb,
                                              const unsigned short* __restrict__ xT,
                                              unsigned short* __restrict__ qkv) {
  __shared__ uint4 lds4[2048];     // 32 KB: A-tile 16 KB | B-tile 16 KB
  char* lds = (char*)lds4;
  char* ldsA = lds;
  char* ldsB = lds + 16384;
  const int bi = blockIdx.x;                 // 0..4799
  const int xcd = bi & 7, g = bi >> 3;       // g: 0..599
  const int bgrp = g / 150;
  const int rem = g - bgrp * 150;
  const int b = xcd + 8 * bgrp;
  const int ot = rem / 25;
  const int pt = rem - ot * 25;
  const int p0 = pt * 128, o0 = ot * 128;
  const bool isv = (ot >= 4);
  const float qs = (ot < 2) ? 0.18033688011112042f : 1.0f;  // SCALE*log2(e)

  const int tid = threadIdx.x;
  const int lane = tid & 63, wave = tid >> 6;
  const int lid = lane & 15, quad = lane >> 4;
  const int m_off = (wave & 1) * 64, n_off = (wave >> 1) * 64;
  const int psub = lane >> 3, chunk = lane & 7;
  const size_t rowb = (size_t)(b * 3136 + p0);
  const char* xTb = (const char*)xT;
  const char* Wbb = (const char*)Wb;

  f32x4 acc[4][4];
#pragma unroll
  for (int mi = 0; mi < 4; mi++)
#pragma unroll
    for (int ni = 0; ni < 4; ni++) { f32x4 z = {0.f, 0.f, 0.f, 0.f}; acc[mi][ni] = z; }

  for (int kk = 0; kk < 256; kk += 64) {
#pragma unroll
    for (int r = 0; r < 4; r++) {
      int i = wave * 4 + r;
      const char* ga = Wbb + (size_t)(o0 + i * 8 + psub) * 512 + kk * 2 + chunk * 16;
      async16(ga, ldsA + i * 1024);
      const char* gb = xTb + (rowb + i * 8 + psub) * 512 + kk * 2 + chunk * 16;
      async16(gb, ldsB + i * 1024);
    }
    __syncthreads();

    V16 a[4][2], bf[4][2];
#pragma unroll
    for (int mi = 0; mi < 4; mi++) {
      int ro = m_off + mi * 16 + lid;
#pragma unroll
      for (int ks = 0; ks < 2; ks++) {
        int gl = ks * 4 + quad;
        a[mi][ks].u = *(const uint4*)(ldsA + ro * 128 + ((gl ^ (ro & 7)) << 4));
      }
    }
#pragma unroll
    for (int ni = 0; ni < 4; ni++) {
      int px = n_off + ni * 16 + lid;
#pragma unroll
      for (int ks = 0; ks < 2; ks++) {
        int gl = ks * 4 + quad;
        bf[ni][ks].u = *(const uint4*)(ldsB + px * 128 + ((gl ^ (px & 7)) << 4));
      }
    }
#pragma unroll
    for (int mi = 0; mi < 4; mi++)
#pragma unroll
      for (int ni = 0; ni < 4; ni++) {
        acc[mi][ni] = __builtin_amdgcn_mfma_f32_16x16x32_bf16(a[mi][0].s, bf[ni][0].s, acc[mi][ni], 0, 0, 0);
        acc[mi][ni] = __builtin_amdgcn_mfma_f32_16x16x32_bf16(a[mi][1].s, bf[ni][1].s, acc[mi][ni], 0, 0, 0);
      }
    __syncthreads();   // releases LDS for next stage (and for the epilogue)
  }

  // ---- epilogue: stage bf16 tile [128 px][256 B of ch] in LDS (swizzled,
  //      reusing the staging buffer - safe after the loop's final barrier),
  //      then write qkv as contiguous 256 B channel segments per pixel ----
#pragma unroll
  for (int mi = 0; mi < 4; mi++) {
    const int chunkb = (m_off >> 3) + mi * 2 + (quad >> 1);
#pragma unroll
    for (int ni = 0; ni < 4; ni++) {
      const int pxl = n_off + ni * 16 + lid;
      f32x4 v = acc[mi][ni];
      v.x *= qs; v.y *= qs; v.z *= qs; v.w *= qs;
      if (isv) {
        v.x = fmaxf(v.x, 0.f); v.y = fmaxf(v.y, 0.f);
        v.z = fmaxf(v.z, 0.f); v.w = fmaxf(v.w, 0.f);
      }
      uint32_t lo = (uint32_t)f2bf(v.x) | ((uint32_t)f2bf(v.y) << 16);
      uint32_t hi = (uint32_t)f2bf(v.z) | ((uint32_t)f2bf(v.w) << 16);
      uint2 st; st.x = lo; st.y = hi;
      *(uint2*)(lds + pxl * 256 + ((chunkb ^ (pxl & 7)) << 4) + (quad & 1) * 8) = st;
    }
  }
  __syncthreads();

#pragma unroll
  for (int rep = 0; rep < 8; rep++) {
    int idx = rep * 256 + tid;
    int pxl = idx >> 4, seg = idx & 15;
    uint4 vv = *(const uint4*)(lds + pxl * 256 + ((seg ^ (pxl & 7)) << 4));
    int px = p0 + pxl;
    if (px < 3136)
      *(uint4*)((char*)qkv + ((size_t)(b * 3136 + px)) * 1536 + o0 * 2 + seg * 16) = vv;
  }
}

// --------------------------- kernel 3: attention ----------------------------
// One block per (window, batch), XCD-batch affinity; wave = head.
// Operand-swapped score: St = K Q^T (MFMA, C rows=key cols=q), so each lane
// holds 4 ADJACENT keys for a fixed q -> P packed as b64 LDS writes, masking
// only in the statically-known mi==3 tile.
// PART: 0=remote (dilated), 1=close (contiguous).
// FUSED: close pass reads oPrev (=oR) and writes fp32 NCHW out directly.
template <int PART, int FUSED>
__global__ __launch_bounds__(256) void k_attn_t(const unsigned short* __restrict__ qkv,
                                                const unsigned short* __restrict__ oPrev,
                                                unsigned short* __restrict__ oDst,
                                                float* __restrict__ out) {
  __shared__ uint4 smem4[2048];   // 32 KB = 4 waves x 8 KB P-buffer
  const int bi = blockIdx.x;                  // 0..2047
  const int xcd = bi & 7, g = bi >> 3;        // g: 0..255
  const int b = ((g >> 6) << 3) + xcd;        // batch: b%8 == xcd
  const int w = g & 63;
  const int i1 = w >> 3, i2 = w & 7;
  const int off = PART ? (i1 * 392 + i2 * 7) : (i1 * 56 + i2);
  const int sh  = PART ? 56 : 448;            // compile-time per instantiation
  const int sw  = PART ? 1 : 8;

  const int lane = threadIdx.x & 63;
  const int head = threadIdx.x >> 6;
  const int lid = lane & 15, quad = lane >> 4;
  char* Pb = (char*)smem4 + head * 8192;
  const unsigned short* __restrict__ qkvb = qkv + (size_t)b * 3136 * 768;

  auto pix = [&](int t) -> int {  // window slot t (0..48) -> pixel index
    int h1 = (t * 37) >> 8;       // t/7 for t<=48
    int w1 = t - h1 * 7;
    return off + h1 * sh + w1 * sw;
  };

  // --- V^T A-frags: A[m=ch][k=key]; lane m=lid -> ch = mi*16+lid ---
  V16 va[4][2];
#pragma unroll
  for (int ks = 0; ks < 2; ks++)
#pragma unroll
    for (int j = 0; j < 8; j++) {
      int key = ks * 32 + quad * 8 + j;
      int p = pix(min(key, 48));               // clamp; P cols >=49 are 0
      const unsigned short* vp = qkvb + p * 768 + 512 + head * 64 + lid;
#pragma unroll
      for (int mi = 0; mi < 4; mi++) va[mi][ks].h[j] = vp[mi * 16];
    }

  // --- Q / K frags (16B per lane). K is the A operand (rows=key). ---
  V16 qf[4][2], kf[4][2];
#pragma unroll
  for (int mi = 0; mi < 4; mi++) {
    int p = pix(min(mi * 16 + lid, 48));
    const unsigned short* qp = qkvb + p * 768 + head * 64;
#pragma unroll
    for (int ks = 0; ks < 2; ks++) qf[mi][ks].u = *(const uint4*)(qp + ks * 32 + quad * 8);
  }
#pragma unroll
  for (int ni = 0; ni < 4; ni++) {
    int p = pix(min(ni * 16 + lid, 48));
    const unsigned short* kp = qkvb + p * 768 + 256 + head * 64;
#pragma unroll
    for (int ks = 0; ks < 2; ks++) kf[ni][ks].u = *(const uint4*)(kp + ks * 32 + quad * 8);
  }

  // --- St = K Q^T (q pre-scaled by SCALE*log2e in k_conv) ---
  //     lane holds St[key = mi*16+quad*4+r][q = ni*16+lid]
  f32x4 s[4][4];
#pragma unroll
  for (int mi = 0; mi < 4; mi++)
#pragma unroll
    for (int ni = 0; ni < 4; ni++) {
      f32x4 z = {0.f, 0.f, 0.f, 0.f};
      z = __builtin_amdgcn_mfma_f32_16x16x32_bf16(kf[mi][0].s, qf[ni][0].s, z, 0, 0, 0);
      z = __builtin_amdgcn_mfma_f32_16x16x32_bf16(kf[mi][1].s, qf[ni][1].s, z, 0, 0, 0);
      s[mi][ni] = z;
    }

  // --- unnormalized P = exp2(St): 4 adjacent keys/lane -> packed b64 writes
  //     into row-major-swizzled P[q][key] (same layout the pt reads expect).
  //     Keys >= 49 exist only in mi==3 (valid only quad==0, r==0). ---
  {
    const int rx = lid & 7;
    char* wbase = Pb + lid * 128 + (quad & 1) * 8;
#pragma unroll
    for (int mi = 0; mi < 4; mi++) {
      const int swz = ((mi * 2 + (quad >> 1)) ^ rx) << 4;
#pragma unroll
      for (int ni = 0; ni < 4; ni++) {
        uint32_t d0, d1;
        if (mi < 3) {
          d0 = (uint32_t)f2bf_rhu(__builtin_amdgcn_exp2f(s[mi][ni][0]))
             | ((uint32_t)f2bf_rhu(__builtin_amdgcn_exp2f(s[mi][ni][1])) << 16);
          d1 = (uint32_t)f2bf_rhu(__builtin_amdgcn_exp2f(s[mi][ni][2]))
             | ((uint32_t)f2bf_rhu(__builtin_amdgcn_exp2f(s[mi][ni][3])) << 16);
        } else {
          d0 = quad ? 0u : (uint32_t)f2bf_rhu(__builtin_amdgcn_exp2f(s[3][ni][0]));
          d1 = 0u;
        }
        uint2 st; st.x = d0; st.y = d1;
        *(uint2*)(wbase + ni * 2048 + swz) = st;
      }
    }
  }
  __syncthreads();   // DS ordering fence (writes above are re-read below)

  // --- P^T B-frags: B[k=key][n=q]; lane n=lid -> q = ni*16+lid ---
  V16 pt[4][2];
#pragma unroll
  for (int ni = 0; ni < 4; ni++) {
    int row = ni * 16 + lid;                   // q row of P
#pragma unroll
    for (int ks = 0; ks < 2; ks++) {
      int gl = ks * 4 + quad;
      pt[ni][ks].u = *(const uint4*)(Pb + row * 128 + ((gl ^ (row & 7)) << 4));
    }
  }

  // --- rowsum(q) via ones-A MFMA: D[.][q] = sum_k P^T[k][q] ---
  V16 ones;
#pragma unroll
  for (int j = 0; j < 8; j++) ones.h[j] = 0x3F80;   // bf16 1.0
  float inv[4];
  int pq[4]; bool qv[4];
#pragma unroll
  for (int ni = 0; ni < 4; ni++) {
    f32x4 z = {0.f, 0.f, 0.f, 0.f};
    z = __builtin_amdgcn_mfma_f32_16x16x32_bf16(ones.s, pt[ni][0].s, z, 0, 0, 0);
    z = __builtin_amdgcn_mfma_f32_16x16x32_bf16(ones.s, pt[ni][1].s, z, 0, 0, 0);
    inv[ni] = __builtin_amdgcn_rcpf(z[0]);
    int q = ni * 16 + lid;
    qv[ni] = q < 49;
    pq[ni] = pix(qv[ni] ? q : 48);
  }

  // --- O^T = V^T P^T; C-layout: row=ch (4 consecutive per lane), col=q ---
#pragma unroll
  for (int mi = 0; mi < 4; mi++) {
    f32x4 om[4];
#pragma unroll
    for (int ni = 0; ni < 4; ni++) {
      f32x4 z = {0.f, 0.f, 0.f, 0.f};
      z = __builtin_amdgcn_mfma_f32_16x16x32_bf16(va[mi][0].s, pt[ni][0].s, z, 0, 0, 0);
      z = __builtin_amdgcn_mfma_f32_16x16x32_bf16(va[mi][1].s, pt[ni][1].s, z, 0, 0, 0);
      om[ni] = z;
    }
    if constexpr (!FUSED) {
      // remote pass: bf16 pixel-major store
      unsigned short* __restrict__ oSb = oDst + (size_t)b * 3136 * 256;
#pragma unroll
      for (int ni = 0; ni < 4; ni++) {
        if (qv[ni]) {
          float iv = inv[ni];
          uint32_t lo = ((uint32_t)f2bf_rhu(om[ni][0] * iv)) | ((uint32_t)f2bf_rhu(om[ni][1] * iv) << 16);
          uint32_t hi = ((uint32_t)f2bf_rhu(om[ni][2] * iv)) | ((uint32_t)f2bf_rhu(om[ni][3] * iv) << 16);
          uint2 st; st.x = lo; st.y = hi;
          *(uint2*)(oSb + pq[ni] * 256 + head * 64 + mi * 16 + quad * 4) = st;
        }
      }
    } else {
      // close pass: add remote result (bf16, pixel-major) and write fp32 NCHW
      const unsigned short* __restrict__ oPb = oPrev + (size_t)b * 3136 * 256;
      float* __restrict__ outb = out + (size_t)b * 256 * 3136;
      const int c0 = head * 64 + mi * 16 + quad * 4;
#pragma unroll
      for (int ni = 0; ni < 4; ni++) {
        if (qv[ni]) {
          float iv = inv[ni];
          uint2 r = *(const uint2*)(oPb + pq[ni] * 256 + c0);
          float o0 = om[ni][0] * iv + bf2f(r.x << 16);
          float o1 = om[ni][1] * iv + bf2f(r.x & 0xFFFF0000u);
          float o2 = om[ni][2] * iv + bf2f(r.y << 16);
          float o3 = om[ni][3] * iv + bf2f(r.y & 0xFFFF0000u);
          float* op = outb + (size_t)c0 * 3136 + pq[ni];
          op[0]        = o0;
          op[3136]     = o1;
          op[2 * 3136] = o2;
          op[3 * 3136] = o3;
        }
      }
    }
  }
}

// ------------------------------- launcher -----------------------------------
extern "C" void kernel_launch(void* const* d_in, const int* in_sizes, int n_in,
                              void* d_out, int out_size, void* d_ws, size_t ws_size,
                              hipStream_t stream) {
  (void)in_sizes; (void)n_in; (void)out_size; (void)ws_size;
  const float* x    = (const float*)d_in[0];
  const float* qk_w = (const float*)d_in[1];
  const float* v_w  = (const float*)d_in[2];
  float* out = (float*)d_out;
  char* ws = (char*)d_ws;
  unsigned short* Wb  = (unsigned short*)ws;                    //     393,216 B
  unsigned short* xT  = (unsigned short*)(ws + 393216);         //  51,380,224 B (reused as oR)
  unsigned short* qkv = (unsigned short*)(ws + 51773440ull);    // 154,140,672 B
  unsigned short* oR  = xT;                                     // alias (xT dead after k_conv)

  hipLaunchKernelGGL(k_wconv, dim3(96), dim3(256), 0, stream, qk_w, v_w, Wb);
  hipLaunchKernelGGL(k_xpose, dim3(49, 8, 32), dim3(256), 0, stream, x, xT);
  hipLaunchKernelGGL(k_conv, dim3(4800), dim3(256), 0, stream, Wb, xT, qkv);
  hipLaunchKernelGGL(HIP_KERNEL_NAME(k_attn_t<0, 0>), dim3(2048), dim3(256), 0, stream,
                     qkv, (const unsigned short*)nullptr, oR, (float*)nullptr);
  hipLaunchKernelGGL(HIP_KERNEL_NAME(k_attn_t<1, 1>), dim3(2048), dim3(256), 0, stream,
                     qkv, (const unsigned short*)oR, (unsigned short*)nullptr, out);
}